// Round 1
// baseline (280.726 us; speedup 1.0000x reference)
//
#include <hip/hip_runtime.h>
#include <hip/hip_bf16.h>
#include <stdint.h>

#define TKS    4096   // tokens = 2*2048
#define KD     4096   // in_features
#define NSF    410    // split_f
#define NPARTS 10
#define NPAD   512    // padded Wfc rows
#define OUTF   4096

#define BM 64
#define BN 128
#define BK 64

typedef unsigned short u16;
typedef __attribute__((ext_vector_type(8))) short bf16x8;
typedef __attribute__((ext_vector_type(4))) float f32x4;

// ---- workspace layout (≈4.4 MB) ----
#define WS_WFC 0                                   // u16[512*4096]
#define WS_G   ((size_t)NPAD * KD * 2)             // float[512*10]
#define WS_C   (WS_G + (size_t)NPAD * NPARTS * 4)  // float[512]
#define WS_SX  (WS_C + (size_t)NPAD * 4)           // float[4096*10]

__device__ inline u16 f2bf(float f) {
    union { __hip_bfloat16 b; u16 u; } cv;
    cv.b = __float2bfloat16(f);
    return cv.u;
}

typedef __attribute__((address_space(3))) unsigned int as3_uint;
typedef __attribute__((address_space(1))) unsigned int as1_uint;
__device__ inline void gl_lds16(const void* g, void* l) {
    __builtin_amdgcn_global_load_lds((as1_uint*)(uintptr_t)g,
                                     (as3_uint*)(uintptr_t)l, 16, 0, 0);
}

// ============ K1: sx[t][n] = x[t]·Wsel[n] + bsel[n]  (f32 exact) ============
// grid 256 blocks × 16 tokens; Wsel staged in LDS by 1024-wide K-chunks.
__global__ __launch_bounds__(256) void sel_kernel(const float* __restrict__ x,
                                                  const float* __restrict__ Wsel,
                                                  const float* __restrict__ bsel,
                                                  float* __restrict__ sx) {
    __shared__ float wsl[NPARTS][1024];
    const int tid = threadIdx.x;
    const int tb  = blockIdx.x;          // tokens tb*16 .. +15
    const int t_l = tid >> 4;            // token within block
    const int g   = tid & 15;            // k-lane within token group

    float acc[NPARTS];
#pragma unroll
    for (int n = 0; n < NPARTS; ++n) acc[n] = 0.f;

    const float* xrow = x + (size_t)(tb * 16 + t_l) * KD;

    for (int kc = 0; kc < 4; ++kc) {
        __syncthreads();
#pragma unroll
        for (int it = 0; it < 10; ++it) {
            int idx = it * 256 + tid;    // float4 index 0..2559
            int n  = idx >> 8;
            int c4 = idx & 255;
            *(float4*)&wsl[n][c4 * 4] =
                *(const float4*)&Wsel[n * KD + kc * 1024 + c4 * 4];
        }
        __syncthreads();
#pragma unroll
        for (int i = 0; i < 16; ++i) {
            int kl = i * 64 + g * 4;
            float4 xv = *(const float4*)&xrow[kc * 1024 + kl];
#pragma unroll
            for (int n = 0; n < NPARTS; ++n) {
                float4 wv = *(float4*)&wsl[n][kl];
                acc[n] += xv.x * wv.x + xv.y * wv.y + xv.z * wv.z + xv.w * wv.w;
            }
        }
    }
#pragma unroll
    for (int off = 8; off >= 1; off >>= 1)
#pragma unroll
        for (int n = 0; n < NPARTS; ++n) acc[n] += __shfl_xor(acc[n], off);

    if (g == 0) {
#pragma unroll
        for (int n = 0; n < NPARTS; ++n)
            sx[(tb * 16 + t_l) * NPARTS + n] = acc[n] + bsel[n];
    }
}

// ============ K2: G[f][n] = Wfc[f]·Wexp[:,n]; c[f] = Wfc[f]·bexp + bfc[f];
//              Wfc -> bf16 (rows >= 410 zero-padded) ============
__global__ __launch_bounds__(256) void prep_kernel(const float* __restrict__ Wfc,
                                                   const float* __restrict__ bfc,
                                                   const float* __restrict__ Wexp,
                                                   const float* __restrict__ bexp,
                                                   u16*   __restrict__ wfcb,
                                                   float* __restrict__ G,
                                                   float* __restrict__ c) {
    const int f = blockIdx.x;            // 0..511
    const int tid = threadIdx.x;
    if (f >= NSF) {
        uint4 z = make_uint4(0u, 0u, 0u, 0u);
#pragma unroll
        for (int i = 0; i < 2; ++i)
            *(uint4*)&wfcb[(size_t)f * KD + (size_t)(tid + i * 256) * 8] = z;
        if (tid < NPARTS) G[f * NPARTS + tid] = 0.f;
        if (tid == 0) c[f] = 0.f;
        return;
    }
    const float* wrow = Wfc + (size_t)f * KD;
    const int k0 = tid * 16;

    float v[16];
#pragma unroll
    for (int i = 0; i < 4; ++i) {
        float4 t = *(const float4*)&wrow[k0 + i * 4];
        v[i * 4 + 0] = t.x; v[i * 4 + 1] = t.y;
        v[i * 4 + 2] = t.z; v[i * 4 + 3] = t.w;
    }
    u16 h[16];
#pragma unroll
    for (int i = 0; i < 16; ++i) h[i] = f2bf(v[i]);
    *(uint4*)&wfcb[(size_t)f * KD + k0]     = *(uint4*)&h[0];
    *(uint4*)&wfcb[(size_t)f * KD + k0 + 8] = *(uint4*)&h[8];

    float accn[NPARTS];
#pragma unroll
    for (int n = 0; n < NPARTS; ++n) accn[n] = 0.f;
    float accb = 0.f;
#pragma unroll
    for (int i = 0; i < 16; ++i) {
        float wv = v[i];
        int k = k0 + i;
        accb += wv * bexp[k];
#pragma unroll
        for (int n = 0; n < NPARTS; ++n) accn[n] += wv * Wexp[k * NPARTS + n];
    }
#pragma unroll
    for (int off = 32; off >= 1; off >>= 1) {
        accb += __shfl_xor(accb, off);
#pragma unroll
        for (int n = 0; n < NPARTS; ++n) accn[n] += __shfl_xor(accn[n], off);
    }
    __shared__ float red[4][NPARTS + 1];
    const int w = tid >> 6, lane = tid & 63;
    if (lane == 0) {
#pragma unroll
        for (int n = 0; n < NPARTS; ++n) red[w][n] = accn[n];
        red[w][NPARTS] = accb;
    }
    __syncthreads();
    if (tid < NPARTS)
        G[f * NPARTS + tid] = red[0][tid] + red[1][tid] + red[2][tid] + red[3][tid];
    if (tid == NPARTS)
        c[f] = red[0][NPARTS] + red[1][NPARTS] + red[2][NPARTS] + red[3][NPARTS] + bfc[f];
}

// ============ K3: A = x·Wfc^T (bf16 MFMA) + fused affine epilogue ============
// grid: 64 token-blocks × 4 f-blocks (fb in low bits for x reuse in cache)
__global__ __launch_bounds__(256) void main_kernel(const float* __restrict__ x,
                                                   const u16*   __restrict__ wfcb,
                                                   const float* __restrict__ G,
                                                   const float* __restrict__ cvec,
                                                   const float* __restrict__ sx,
                                                   float* __restrict__ out) {
    __shared__ __align__(16) u16 As[BM * BK];   // [64][64] row-major, 8 KB
    __shared__ __align__(16) u16 Bs[BN * BK];   // [128][64] row-major, 16 KB
    __shared__ float sxs[BM][NPARTS];
    __shared__ float Gs[BN][NPARTS];
    __shared__ float cs[BN];

    const int tid = threadIdx.x;
    const int bid = blockIdx.x;
    const int fb  = bid & 3;
    const int tb  = bid >> 2;

    const int lane = tid & 63;
    const int w  = tid >> 6;
    const int wr = w >> 1;   // token half (0/1)
    const int wc = w & 1;    // f half (0/1)
    const int q  = lane >> 4;
    const int ml = lane & 15;

    f32x4 acc[2][4];
#pragma unroll
    for (int mi = 0; mi < 2; ++mi)
#pragma unroll
        for (int ni = 0; ni < 4; ++ni) acc[mi][ni] = (f32x4){0.f, 0.f, 0.f, 0.f};

    // A staging addresses: thread covers rows (tid>>3) and (tid>>3)+32, 8 cols
    const int arow = tid >> 3;
    const int acol = (tid & 7) * 8;
    const float* ag0 = x + (size_t)(tb * BM + arow) * KD + acol;
    const float* ag1 = ag0 + (size_t)32 * KD;
    u16* as0 = &As[arow * BK + acol];
    u16* as1 = &As[(arow + 32) * BK + acol];

    // B staging via global_load_lds: 4 calls × 256 thr × 16 B = 16 KB
    const u16* bg[4];
    u16* bl[4];
#pragma unroll
    for (int cc = 0; cc < 4; ++cc) {
        int e = (cc * 256 + tid) * 8;
        int row = e >> 6, col = e & 63;
        bg[cc] = wfcb + (size_t)(fb * BN + row) * KD + col;
        bl[cc] = &Bs[e];
    }

    for (int kt = 0; kt < KD / BK; ++kt) {
        const int koff = kt * BK;
        __syncthreads();
#pragma unroll
        for (int cc = 0; cc < 4; ++cc) gl_lds16(bg[cc] + koff, bl[cc]);

        float4 a0 = *(const float4*)(ag0 + koff);
        float4 a1 = *(const float4*)(ag0 + koff + 4);
        float4 a2 = *(const float4*)(ag1 + koff);
        float4 a3 = *(const float4*)(ag1 + koff + 4);
        u16 h0[8], h1[8];
        h0[0]=f2bf(a0.x); h0[1]=f2bf(a0.y); h0[2]=f2bf(a0.z); h0[3]=f2bf(a0.w);
        h0[4]=f2bf(a1.x); h0[5]=f2bf(a1.y); h0[6]=f2bf(a1.z); h0[7]=f2bf(a1.w);
        h1[0]=f2bf(a2.x); h1[1]=f2bf(a2.y); h1[2]=f2bf(a2.z); h1[3]=f2bf(a2.w);
        h1[4]=f2bf(a3.x); h1[5]=f2bf(a3.y); h1[6]=f2bf(a3.z); h1[7]=f2bf(a3.w);
        *(uint4*)as0 = *(uint4*)&h0[0];
        *(uint4*)as1 = *(uint4*)&h1[0];
        __syncthreads();

#pragma unroll
        for (int ks = 0; ks < 2; ++ks) {
            bf16x8 av[2], bv[4];
#pragma unroll
            for (int mi = 0; mi < 2; ++mi)
                av[mi] = *(const bf16x8*)&As[(wr * 32 + mi * 16 + ml) * BK + ks * 32 + q * 8];
#pragma unroll
            for (int ni = 0; ni < 4; ++ni)
                bv[ni] = *(const bf16x8*)&Bs[(wc * 64 + ni * 16 + ml) * BK + ks * 32 + q * 8];
#pragma unroll
            for (int mi = 0; mi < 2; ++mi)
#pragma unroll
                for (int ni = 0; ni < 4; ++ni)
                    acc[mi][ni] = __builtin_amdgcn_mfma_f32_16x16x32_bf16(
                        av[mi], bv[ni], acc[mi][ni], 0, 0, 0);
        }
    }

    // ---- epilogue: out[t, n*410+f] = A + sx[t][n]*G[f][n] + c[f] ----
    __syncthreads();
    for (int idx = tid; idx < BM * NPARTS; idx += 256)
        sxs[idx / NPARTS][idx % NPARTS] = sx[(tb * BM + idx / NPARTS) * NPARTS + idx % NPARTS];
    for (int idx = tid; idx < BN * NPARTS; idx += 256)
        Gs[idx / NPARTS][idx % NPARTS] = G[(fb * BN + idx / NPARTS) * NPARTS + idx % NPARTS];
    if (tid < BN) cs[tid] = cvec[fb * BN + tid];
    __syncthreads();

#pragma unroll
    for (int ni = 0; ni < 4; ++ni) {
        const int fl = wc * 64 + ni * 16 + ml;
        const int fg = fb * BN + fl;
        if (fg >= NSF) continue;
        const float cv = cs[fl];
        float gv[NPARTS];
#pragma unroll
        for (int n = 0; n < NPARTS; ++n) gv[n] = Gs[fl][n];
#pragma unroll
        for (int mi = 0; mi < 2; ++mi) {
#pragma unroll
            for (int r = 0; r < 4; ++r) {
                const int tl = wr * 32 + mi * 16 + q * 4 + r;
                const float av = acc[mi][ni][r] + cv;
                float* orow = out + (size_t)(tb * BM + tl) * OUTF;
#pragma unroll
                for (int n = 0; n < NPARTS; ++n) {
                    int j = n * NSF + fg;
                    if (j < OUTF) orow[j] = av + sxs[tl][n] * gv[n];
                }
            }
        }
    }
}

extern "C" void kernel_launch(void* const* d_in, const int* in_sizes, int n_in,
                              void* d_out, int out_size, void* d_ws, size_t ws_size,
                              hipStream_t stream) {
    const float* x    = (const float*)d_in[0];
    const float* Wsel = (const float*)d_in[1];
    const float* bsel = (const float*)d_in[2];
    const float* Wexp = (const float*)d_in[3];
    const float* bexp = (const float*)d_in[4];
    const float* Wfc  = (const float*)d_in[5];
    const float* bfc  = (const float*)d_in[6];
    float* out = (float*)d_out;

    char* ws = (char*)d_ws;
    u16*   wfcb = (u16*)  (ws + WS_WFC);
    float* G    = (float*)(ws + WS_G);
    float* c    = (float*)(ws + WS_C);
    float* sx   = (float*)(ws + WS_SX);

    sel_kernel<<<dim3(TKS / 16), dim3(256), 0, stream>>>(x, Wsel, bsel, sx);
    prep_kernel<<<dim3(NPAD), dim3(256), 0, stream>>>(Wfc, bfc, Wexp, bexp, wfcb, G, c);
    main_kernel<<<dim3((TKS / BM) * 4), dim3(256), 0, stream>>>(x, wfcb, G, c, sx, out);
}

// Round 2
// 260.703 us; speedup vs baseline: 1.0768x; 1.0768x over previous
//
#include <hip/hip_runtime.h>
#include <hip/hip_bf16.h>
#include <stdint.h>

#define TKS    4096   // tokens = 2*2048
#define KD     4096   // in_features
#define NSF    410    // split_f
#define NPARTS 10
#define NPAD   512    // padded Wfc rows
#define OUTF   4096

#define BM 64
#define BN 64
#define BK 64

typedef unsigned short u16;
typedef __attribute__((ext_vector_type(8))) short bf16x8;
typedef __attribute__((ext_vector_type(4))) float f32x4;

// ---- workspace layout (~4.4 MB) ----
#define WS_WFC 0                                    // u16[512*4096]
#define WS_G   ((size_t)NPAD * KD * 2)              // float[512*10]
#define WS_C   (WS_G + (size_t)NPAD * NPARTS * 4)   // float[512]
#define WS_SX  (WS_C + (size_t)NPAD * 4)            // float[4096*10]
#define WS_WT  (WS_SX + (size_t)TKS * NPARTS * 4)   // float[11*4096]

__device__ inline u16 f2bf(float f) {
    union { __hip_bfloat16 b; u16 u; } cv;
    cv.b = __float2bfloat16(f);
    return cv.u;
}

typedef __attribute__((address_space(3))) unsigned int as3_uint;
typedef __attribute__((address_space(1))) unsigned int as1_uint;
__device__ inline void gl_lds16(const void* g, void* l) {
    __builtin_amdgcn_global_load_lds((as1_uint*)(uintptr_t)g,
                                     (as3_uint*)(uintptr_t)l, 16, 0, 0);
}

// granule index g in [0,512) -> (row, col) of a 64x64 tile.
// g = slot*64 + q*16 + ml ; slot = (hi*2 + ks)*2 + lo
// row = hi*32 + lo*16 + ml ; col = ks*32 + q*8
// MFMA read for (hi, lo, ks): addr = (slot*64 + lane)*16B  -> conflict-free.
__device__ inline int g_row(int g) { int s = g >> 6; return (s >> 2) * 32 + (s & 1) * 16 + (g & 15); }
__device__ inline int g_col(int g) { int s = g >> 6; return ((s >> 1) & 1) * 32 + ((g >> 4) & 3) * 8; }

// ============ sel: sx[t][n] = x[t]·Wsel[n] + bsel[n]  (f32 exact) ============
// 512 blocks; each wave handles 2 tokens (Wsel LDS read reused for both).
__global__ __launch_bounds__(256) void sel_kernel(const float* __restrict__ x,
                                                  const float* __restrict__ Wsel,
                                                  const float* __restrict__ bsel,
                                                  float* __restrict__ sx) {
    __shared__ float wsl[NPARTS][512];
    const int tid  = threadIdx.x;
    const int lane = tid & 63;
    const int w    = tid >> 6;
    const int t0   = blockIdx.x * 8 + w * 2;

    float acc0[NPARTS], acc1[NPARTS];
#pragma unroll
    for (int n = 0; n < NPARTS; ++n) { acc0[n] = 0.f; acc1[n] = 0.f; }

    const float* xr0 = x + (size_t)t0 * KD;
    const float* xr1 = xr0 + KD;

    for (int ch = 0; ch < 8; ++ch) {
        __syncthreads();
#pragma unroll
        for (int it = 0; it < 5; ++it) {
            int idx = it * 256 + tid;          // 0..1279 float4 slots
            int n = idx >> 7, c4 = (idx & 127) * 4;
            *(float4*)&wsl[n][c4] = *(const float4*)&Wsel[n * KD + ch * 512 + c4];
        }
        __syncthreads();
#pragma unroll
        for (int j = 0; j < 2; ++j) {
            int kl = j * 256 + lane * 4;       // contiguous lane*16B
            float4 x0 = *(const float4*)&xr0[ch * 512 + kl];
            float4 x1 = *(const float4*)&xr1[ch * 512 + kl];
#pragma unroll
            for (int n = 0; n < NPARTS; ++n) {
                float4 wv = *(float4*)&wsl[n][kl];
                acc0[n] += x0.x * wv.x + x0.y * wv.y + x0.z * wv.z + x0.w * wv.w;
                acc1[n] += x1.x * wv.x + x1.y * wv.y + x1.z * wv.z + x1.w * wv.w;
            }
        }
    }
#pragma unroll
    for (int off = 32; off >= 1; off >>= 1)
#pragma unroll
        for (int n = 0; n < NPARTS; ++n) {
            acc0[n] += __shfl_xor(acc0[n], off);
            acc1[n] += __shfl_xor(acc1[n], off);
        }
    if (lane == 0) {
#pragma unroll
        for (int n = 0; n < NPARTS; ++n) {
            float bs = bsel[n];
            sx[(size_t)t0 * NPARTS + n]       = acc0[n] + bs;
            sx[(size_t)(t0 + 1) * NPARTS + n] = acc1[n] + bs;
        }
    }
}

// ============ prep_a: WT[n][k] = Wexp[k][n] (n<10); WT[10][k] = bexp[k] ======
__global__ __launch_bounds__(256) void prep_a(const float* __restrict__ Wexp,
                                              const float* __restrict__ bexp,
                                              float* __restrict__ WT) {
    const int k = blockIdx.x * 256 + threadIdx.x;   // 0..4095
#pragma unroll
    for (int n = 0; n < NPARTS; ++n) WT[(size_t)n * KD + k] = Wexp[(size_t)k * NPARTS + n];
    WT[(size_t)NPARTS * KD + k] = bexp[k];
}

// ============ prep_b: per f-row: bf16 convert + G/c dots (coalesced) =========
__global__ __launch_bounds__(256) void prep_b(const float* __restrict__ Wfc,
                                              const float* __restrict__ bfc,
                                              const float* __restrict__ WT,
                                              u16*   __restrict__ wfcb,
                                              float* __restrict__ G,
                                              float* __restrict__ c) {
    const int f = blockIdx.x;            // 0..511
    const int tid = threadIdx.x;
    if (f >= NSF) {
        uint4 z = make_uint4(0u, 0u, 0u, 0u);
        *(uint4*)&wfcb[(size_t)f * KD + tid * 8]        = z;
        *(uint4*)&wfcb[(size_t)f * KD + 2048 + tid * 8] = z;
        if (tid < NPARTS) G[(size_t)f * NPARTS + tid] = 0.f;
        if (tid == NPARTS) c[f] = 0.f;
        return;
    }
    float acc[NPARTS + 1];
#pragma unroll
    for (int n = 0; n <= NPARTS; ++n) acc[n] = 0.f;

#pragma unroll
    for (int i = 0; i < 4; ++i) {
        const int k = i * 1024 + tid * 4;
        float4 wv = *(const float4*)&Wfc[(size_t)f * KD + k];
        u16 h[4] = { f2bf(wv.x), f2bf(wv.y), f2bf(wv.z), f2bf(wv.w) };
        *(uint2*)&wfcb[(size_t)f * KD + k] = *(uint2*)h;
#pragma unroll
        for (int n = 0; n <= NPARTS; ++n) {
            float4 t = *(const float4*)&WT[(size_t)n * KD + k];
            acc[n] += wv.x * t.x + wv.y * t.y + wv.z * t.z + wv.w * t.w;
        }
    }
#pragma unroll
    for (int off = 32; off >= 1; off >>= 1)
#pragma unroll
        for (int n = 0; n <= NPARTS; ++n) acc[n] += __shfl_xor(acc[n], off);

    __shared__ float red[4][NPARTS + 1];
    const int w = tid >> 6, lane = tid & 63;
    if (lane == 0) {
#pragma unroll
        for (int n = 0; n <= NPARTS; ++n) red[w][n] = acc[n];
    }
    __syncthreads();
    if (tid < NPARTS)
        G[(size_t)f * NPARTS + tid] = red[0][tid] + red[1][tid] + red[2][tid] + red[3][tid];
    if (tid == NPARTS)
        c[f] = red[0][NPARTS] + red[1][NPARTS] + red[2][NPARTS] + red[3][NPARTS] + bfc[f];
}

// ============ main: A = x·Wfc^T (bf16 MFMA, dbuf, frag-ordered LDS) ==========
// grid 448 = 7 fb × 64 tb ; 4 waves, wave tile 32×32 (wr,wc ∈ {0,1})
__global__ __launch_bounds__(256, 2) void main_kernel(const float* __restrict__ x,
                                                      const u16*   __restrict__ wfcb,
                                                      const float* __restrict__ G,
                                                      const float* __restrict__ cvec,
                                                      const float* __restrict__ sx,
                                                      float* __restrict__ out) {
    __shared__ __align__(16) u16 As[2][4096];   // 2 × 512 granules × 16B = 16 KB
    __shared__ __align__(16) u16 Bs[2][4096];   // 16 KB
    __shared__ float sxs[BM][NPARTS];
    __shared__ float Gs[BN][NPARTS];
    __shared__ float cs[BN];

    const int tid = threadIdx.x;
    const int fb  = blockIdx.x >> 6;    // 0..6
    const int tb  = blockIdx.x & 63;

    const int lane = tid & 63;
    const int w  = tid >> 6;
    const int wr = w >> 1, wc = w & 1;
    const int q  = lane >> 4, ml = lane & 15;

    f32x4 acc[2][2];
#pragma unroll
    for (int mi = 0; mi < 2; ++mi)
#pragma unroll
        for (int ni = 0; ni < 2; ++ni) acc[mi][ni] = (f32x4){0.f, 0.f, 0.f, 0.f};

    // this thread stages granules g0=tid and g1=256+tid of each 64x64 tile
    const int g0 = tid, g1 = 256 + tid;
    const float* ax0 = x + (size_t)(tb * BM + g_row(g0)) * KD + g_col(g0);
    const float* ax1 = x + (size_t)(tb * BM + g_row(g1)) * KD + g_col(g1);
    const u16*   bg0 = wfcb + (size_t)(fb * BN + g_row(g0)) * KD + g_col(g0);
    const u16*   bg1 = wfcb + (size_t)(fb * BN + g_row(g1)) * KD + g_col(g1);

    // epilogue data (visible after first barrier)
    for (int idx = tid; idx < BM * NPARTS; idx += 256)
        sxs[idx / NPARTS][idx % NPARTS] = sx[(size_t)(tb * BM + idx / NPARTS) * NPARTS + idx % NPARTS];
    for (int idx = tid; idx < BN * NPARTS; idx += 256)
        Gs[idx / NPARTS][idx % NPARTS] = G[(size_t)(fb * BN + idx / NPARTS) * NPARTS + idx % NPARTS];
    if (tid < BN) cs[tid] = cvec[fb * BN + tid];

    // prologue: stage kt=0 into buffer 0
    {
        gl_lds16(bg0, &Bs[0][g0 * 8]);
        gl_lds16(bg1, &Bs[0][g1 * 8]);
        float4 a0 = *(const float4*)(ax0);
        float4 a1 = *(const float4*)(ax0 + 4);
        float4 a2 = *(const float4*)(ax1);
        float4 a3 = *(const float4*)(ax1 + 4);
        u16 h0[8] = { f2bf(a0.x), f2bf(a0.y), f2bf(a0.z), f2bf(a0.w),
                      f2bf(a1.x), f2bf(a1.y), f2bf(a1.z), f2bf(a1.w) };
        u16 h1[8] = { f2bf(a2.x), f2bf(a2.y), f2bf(a2.z), f2bf(a2.w),
                      f2bf(a3.x), f2bf(a3.y), f2bf(a3.z), f2bf(a3.w) };
        *(uint4*)&As[0][g0 * 8] = *(uint4*)h0;
        *(uint4*)&As[0][g1 * 8] = *(uint4*)h1;
    }
    __syncthreads();

    int buf = 0;
#pragma unroll 2
    for (int kt = 0; kt < KD / BK; ++kt) {
        const bool pre = (kt + 1) < KD / BK;
        float4 a0, a1, a2, a3;
        if (pre) {
            const int ko = (kt + 1) * BK;
            gl_lds16(bg0 + ko, &Bs[buf ^ 1][g0 * 8]);
            gl_lds16(bg1 + ko, &Bs[buf ^ 1][g1 * 8]);
            a0 = *(const float4*)(ax0 + ko);
            a1 = *(const float4*)(ax0 + ko + 4);
            a2 = *(const float4*)(ax1 + ko);
            a3 = *(const float4*)(ax1 + ko + 4);
        }
#pragma unroll
        for (int ks = 0; ks < 2; ++ks) {
            bf16x8 av[2], bv[2];
#pragma unroll
            for (int mi = 0; mi < 2; ++mi)
                av[mi] = *(const bf16x8*)&As[buf][(((wr * 2 + ks) * 2 + mi) * 64 + lane) * 8];
#pragma unroll
            for (int ni = 0; ni < 2; ++ni)
                bv[ni] = *(const bf16x8*)&Bs[buf][(((wc * 2 + ks) * 2 + ni) * 64 + lane) * 8];
#pragma unroll
            for (int mi = 0; mi < 2; ++mi)
#pragma unroll
                for (int ni = 0; ni < 2; ++ni)
                    acc[mi][ni] = __builtin_amdgcn_mfma_f32_16x16x32_bf16(
                        av[mi], bv[ni], acc[mi][ni], 0, 0, 0);
        }
        if (pre) {
            u16 h0[8] = { f2bf(a0.x), f2bf(a0.y), f2bf(a0.z), f2bf(a0.w),
                          f2bf(a1.x), f2bf(a1.y), f2bf(a1.z), f2bf(a1.w) };
            u16 h1[8] = { f2bf(a2.x), f2bf(a2.y), f2bf(a2.z), f2bf(a2.w),
                          f2bf(a3.x), f2bf(a3.y), f2bf(a3.z), f2bf(a3.w) };
            *(uint4*)&As[buf ^ 1][g0 * 8] = *(uint4*)h0;
            *(uint4*)&As[buf ^ 1][g1 * 8] = *(uint4*)h1;
        }
        __syncthreads();
        buf ^= 1;
    }

    // ---- epilogue: out[t, n*410+f] = A + sx[t][n]*G[f][n] + c[f] ----
#pragma unroll
    for (int ni = 0; ni < 2; ++ni) {
        const int fl = wc * 32 + ni * 16 + ml;
        const int fg = fb * BN + fl;
        if (fg >= NSF) continue;
        const float cv = cs[fl];
        float gv[NPARTS];
#pragma unroll
        for (int n = 0; n < NPARTS; ++n) gv[n] = Gs[fl][n];
#pragma unroll
        for (int mi = 0; mi < 2; ++mi) {
#pragma unroll
            for (int r = 0; r < 4; ++r) {
                const int tl = wr * 32 + mi * 16 + q * 4 + r;
                const float av = acc[mi][ni][r] + cv;
                float* orow = out + (size_t)(tb * BM + tl) * OUTF;
#pragma unroll
                for (int n = 0; n < NPARTS; ++n) {
                    int j = n * NSF + fg;
                    if (j < OUTF) orow[j] = av + sxs[tl][n] * gv[n];
                }
            }
        }
    }
}

extern "C" void kernel_launch(void* const* d_in, const int* in_sizes, int n_in,
                              void* d_out, int out_size, void* d_ws, size_t ws_size,
                              hipStream_t stream) {
    const float* x    = (const float*)d_in[0];
    const float* Wsel = (const float*)d_in[1];
    const float* bsel = (const float*)d_in[2];
    const float* Wexp = (const float*)d_in[3];
    const float* bexp = (const float*)d_in[4];
    const float* Wfc  = (const float*)d_in[5];
    const float* bfc  = (const float*)d_in[6];
    float* out = (float*)d_out;

    char* ws = (char*)d_ws;
    u16*   wfcb = (u16*)  (ws + WS_WFC);
    float* G    = (float*)(ws + WS_G);
    float* c    = (float*)(ws + WS_C);
    float* sx   = (float*)(ws + WS_SX);
    float* WT   = (float*)(ws + WS_WT);

    prep_a<<<dim3(16),  dim3(256), 0, stream>>>(Wexp, bexp, WT);
    sel_kernel<<<dim3(TKS / 8), dim3(256), 0, stream>>>(x, Wsel, bsel, sx);
    prep_b<<<dim3(NPAD), dim3(256), 0, stream>>>(Wfc, bfc, WT, wfcb, G, c);
    main_kernel<<<dim3(7 * 64), dim3(256), 0, stream>>>(x, wfcb, G, c, sx, out);
}

// Round 3
// 224.268 us; speedup vs baseline: 1.2517x; 1.1625x over previous
//
#include <hip/hip_runtime.h>
#include <hip/hip_bf16.h>
#include <stdint.h>

#define TKS    4096   // tokens = 2*2048
#define KD     4096   // in_features
#define NSF    410    // split_f
#define NPARTS 10
#define NPAD   512    // padded Wfc rows (8 row-blocks of 64)
#define OUTF   4096

#define BM 64
#define BN 64
#define BK 128        // two 64-wide granule tiles per K iteration

typedef unsigned short u16;
typedef __attribute__((ext_vector_type(8))) short bf16x8;
typedef __attribute__((ext_vector_type(4))) float f32x4;

// ---- workspace layout (~38.1 MB) ----
#define WS_XB  0                                     // u16[4096*4096] swizzled bf16 x
#define WS_BSW ((size_t)TKS * KD * 2)                // u16[512*4096] swizzled bf16 Wfc
#define WS_G   (WS_BSW + (size_t)NPAD * KD * 2)      // float[512*10]
#define WS_C   (WS_G + (size_t)NPAD * NPARTS * 4)    // float[512]
#define WS_SX  (WS_C + (size_t)NPAD * 4)             // float[4096*10]
#define WS_WT  (WS_SX + (size_t)TKS * NPARTS * 4)    // float[11*4096]

__device__ inline u16 f2bf(float f) {
    union { __hip_bfloat16 b; u16 u; } cv;
    cv.b = __float2bfloat16(f);
    return cv.u;
}

typedef __attribute__((address_space(3))) unsigned int as3_uint;
typedef __attribute__((address_space(1))) unsigned int as1_uint;
__device__ inline void gl_lds16(const void* g, void* l) {
    __builtin_amdgcn_global_load_lds((as1_uint*)(uintptr_t)g,
                                     (as3_uint*)(uintptr_t)l, 16, 0, 0);
}

// granule index g in [0,512) -> (row, col) of a 64x64 tile.
// g = slot*64 + q*16 + ml ; slot = (hi*2 + ks)*2 + lo
// row = hi*32 + lo*16 + ml ; col = ks*32 + q*8
// MFMA read for (hi,lo,ks): addr = (slot*64 + lane)*16B -> conflict-free (proven R2).
__device__ inline int g_row(int g) { int s = g >> 6; return (s >> 2) * 32 + (s & 1) * 16 + (g & 15); }
__device__ inline int g_col(int g) { int s = g >> 6; return ((s >> 1) & 1) * 32 + ((g >> 4) & 3) * 8; }

// ============ retile_x: x (f32 row-major) -> xb (bf16, granule-tiled) ========
// grid 64 tb x 64 kt; writes are linear (tid*16B) -> perfectly coalesced.
__global__ __launch_bounds__(256) void retile_x(const float* __restrict__ x,
                                                u16* __restrict__ xb) {
    const int kt = blockIdx.x & 63, tb = blockIdx.x >> 6;
    const int tid = threadIdx.x;
    const float* tin = x + (size_t)(tb * 64) * KD + kt * 64;
    u16* tout = xb + ((size_t)(tb * 64 + kt) * 512) * 8;
#pragma unroll
    for (int j = 0; j < 2; ++j) {
        const int g = j * 256 + tid;
        const int r = g_row(g), cg = g_col(g);
        float4 v0 = *(const float4*)&tin[(size_t)r * KD + cg];
        float4 v1 = *(const float4*)&tin[(size_t)r * KD + cg + 4];
        u16 h[8] = { f2bf(v0.x), f2bf(v0.y), f2bf(v0.z), f2bf(v0.w),
                     f2bf(v1.x), f2bf(v1.y), f2bf(v1.z), f2bf(v1.w) };
        *(uint4*)&tout[(size_t)g * 8] = *(uint4*)h;
    }
}

// ============ retile_b: Wfc (f32) -> bsw (bf16, granule-tiled, rows>=410 zero)
// grid 7 rb x 64 kt
__global__ __launch_bounds__(256) void retile_b(const float* __restrict__ Wfc,
                                                u16* __restrict__ bsw) {
    const int kt = blockIdx.x & 63, rb = blockIdx.x >> 6;
    const int tid = threadIdx.x;
    u16* tout = bsw + ((size_t)(rb * 64 + kt) * 512) * 8;
#pragma unroll
    for (int j = 0; j < 2; ++j) {
        const int g = j * 256 + tid;
        const int r = rb * 64 + g_row(g);
        uint4 pk = make_uint4(0u, 0u, 0u, 0u);
        if (r < NSF) {
            const float* src = Wfc + (size_t)r * KD + kt * 64 + g_col(g);
            float4 v0 = *(const float4*)src;
            float4 v1 = *(const float4*)(src + 4);
            u16 h[8] = { f2bf(v0.x), f2bf(v0.y), f2bf(v0.z), f2bf(v0.w),
                         f2bf(v1.x), f2bf(v1.y), f2bf(v1.z), f2bf(v1.w) };
            pk = *(uint4*)h;
        }
        *(uint4*)&tout[(size_t)g * 8] = pk;
    }
}

// ============ sel: sx[t][n] = x[t]·Wsel[n] + bsel[n]  (f32 exact) ============
__global__ __launch_bounds__(256) void sel_kernel(const float* __restrict__ x,
                                                  const float* __restrict__ Wsel,
                                                  const float* __restrict__ bsel,
                                                  float* __restrict__ sx) {
    __shared__ float wsl[NPARTS][512];
    const int tid  = threadIdx.x;
    const int lane = tid & 63;
    const int w    = tid >> 6;
    const int t0   = blockIdx.x * 8 + w * 2;

    float acc0[NPARTS], acc1[NPARTS];
#pragma unroll
    for (int n = 0; n < NPARTS; ++n) { acc0[n] = 0.f; acc1[n] = 0.f; }

    const float* xr0 = x + (size_t)t0 * KD;
    const float* xr1 = xr0 + KD;

    for (int ch = 0; ch < 8; ++ch) {
        __syncthreads();
#pragma unroll
        for (int it = 0; it < 5; ++it) {
            int idx = it * 256 + tid;
            int n = idx >> 7, c4 = (idx & 127) * 4;
            *(float4*)&wsl[n][c4] = *(const float4*)&Wsel[n * KD + ch * 512 + c4];
        }
        __syncthreads();
#pragma unroll
        for (int j = 0; j < 2; ++j) {
            int kl = j * 256 + lane * 4;
            float4 x0 = *(const float4*)&xr0[ch * 512 + kl];
            float4 x1 = *(const float4*)&xr1[ch * 512 + kl];
#pragma unroll
            for (int n = 0; n < NPARTS; ++n) {
                float4 wv = *(float4*)&wsl[n][kl];
                acc0[n] += x0.x * wv.x + x0.y * wv.y + x0.z * wv.z + x0.w * wv.w;
                acc1[n] += x1.x * wv.x + x1.y * wv.y + x1.z * wv.z + x1.w * wv.w;
            }
        }
    }
#pragma unroll
    for (int off = 32; off >= 1; off >>= 1)
#pragma unroll
        for (int n = 0; n < NPARTS; ++n) {
            acc0[n] += __shfl_xor(acc0[n], off);
            acc1[n] += __shfl_xor(acc1[n], off);
        }
    if (lane == 0) {
#pragma unroll
        for (int n = 0; n < NPARTS; ++n) {
            float bs = bsel[n];
            sx[(size_t)t0 * NPARTS + n]       = acc0[n] + bs;
            sx[(size_t)(t0 + 1) * NPARTS + n] = acc1[n] + bs;
        }
    }
}

// ============ prep_a: WT[n][k] = Wexp[k][n]; WT[10][k] = bexp[k] =============
__global__ __launch_bounds__(256) void prep_a(const float* __restrict__ Wexp,
                                              const float* __restrict__ bexp,
                                              float* __restrict__ WT) {
    const int k = blockIdx.x * 256 + threadIdx.x;
#pragma unroll
    for (int n = 0; n < NPARTS; ++n) WT[(size_t)n * KD + k] = Wexp[(size_t)k * NPARTS + n];
    WT[(size_t)NPARTS * KD + k] = bexp[k];
}

// ============ prep_b: G[f][n] = Wfc[f]·WT[n]; c[f] = Wfc[f]·bexp + bfc[f] ====
// grid 410 (rows >= 410 never used by the guarded epilogue)
__global__ __launch_bounds__(256) void prep_b(const float* __restrict__ Wfc,
                                              const float* __restrict__ bfc,
                                              const float* __restrict__ WT,
                                              float* __restrict__ G,
                                              float* __restrict__ c) {
    const int f = blockIdx.x;
    const int tid = threadIdx.x;
    float acc[NPARTS + 1];
#pragma unroll
    for (int n = 0; n <= NPARTS; ++n) acc[n] = 0.f;

#pragma unroll
    for (int i = 0; i < 4; ++i) {
        const int k = i * 1024 + tid * 4;
        float4 wv = *(const float4*)&Wfc[(size_t)f * KD + k];
#pragma unroll
        for (int n = 0; n <= NPARTS; ++n) {
            float4 t = *(const float4*)&WT[(size_t)n * KD + k];
            acc[n] += wv.x * t.x + wv.y * t.y + wv.z * t.z + wv.w * t.w;
        }
    }
#pragma unroll
    for (int off = 32; off >= 1; off >>= 1)
#pragma unroll
        for (int n = 0; n <= NPARTS; ++n) acc[n] += __shfl_xor(acc[n], off);

    __shared__ float red[4][NPARTS + 1];
    const int w = tid >> 6, lane = tid & 63;
    if (lane == 0) {
#pragma unroll
        for (int n = 0; n <= NPARTS; ++n) red[w][n] = acc[n];
    }
    __syncthreads();
    if (tid < NPARTS)
        G[(size_t)f * NPARTS + tid] = red[0][tid] + red[1][tid] + red[2][tid] + red[3][tid];
    if (tid == NPARTS)
        c[f] = red[0][NPARTS] + red[1][NPARTS] + red[2][NPARTS] + red[3][NPARTS] + bfc[f];
}

// ============ main: A = x·Wfc^T, both operands pre-swizzled bf16 =============
// grid 448 = 7 fb x 64 tb; BK=128, dbuf; staging = pure global_load_lds (linear)
__global__ __launch_bounds__(256, 2) void main_kernel(const u16* __restrict__ xb,
                                                      const u16* __restrict__ bsw,
                                                      const float* __restrict__ G,
                                                      const float* __restrict__ cvec,
                                                      const float* __restrict__ sx,
                                                      float* __restrict__ out) {
    __shared__ __align__(16) u16 As[2][8192];   // 2 x 16 KB
    __shared__ __align__(16) u16 Bs[2][8192];   // 2 x 16 KB
    __shared__ float sxs[BM][NPARTS];
    __shared__ float Gs[BN][NPARTS];
    __shared__ float cs[BN];

    const int tid = threadIdx.x;
    const int fb  = blockIdx.x >> 6;    // 0..6
    const int tb  = blockIdx.x & 63;

    const int lane = tid & 63;
    const int w  = tid >> 6;
    const int wr = w >> 1, wc = w & 1;
    const int q  = lane >> 4, ml = lane & 15;

    f32x4 acc[2][2];
#pragma unroll
    for (int mi = 0; mi < 2; ++mi)
#pragma unroll
        for (int ni = 0; ni < 2; ++ni) acc[mi][ni] = (f32x4){0.f, 0.f, 0.f, 0.f};

    const u16* abase = xb  + (size_t)tb * 64 * 4096;   // 64 kt-tiles x 512 granules x 8
    const u16* bbase = bsw + (size_t)fb * 64 * 4096;

    // epilogue staging (visible after first barrier)
    for (int idx = tid; idx < BM * NPARTS; idx += 256)
        sxs[idx / NPARTS][idx % NPARTS] = sx[(size_t)(tb * BM + idx / NPARTS) * NPARTS + idx % NPARTS];
    for (int idx = tid; idx < BN * NPARTS; idx += 256)
        Gs[idx / NPARTS][idx % NPARTS] = G[(size_t)(fb * BN + idx / NPARTS) * NPARTS + idx % NPARTS];
    if (tid < BN) cs[tid] = cvec[fb * BN + tid];

    // prologue: stage iteration 0 into buffer 0 (4 KB A + 4 KB B per 64-col tile; BK=128 -> 2 tiles)
#pragma unroll
    for (int k = 0; k < 4; ++k) {
        gl_lds16(abase + (k * 256 + tid) * 8, &As[0][(k * 256 + tid) * 8]);
        gl_lds16(bbase + (k * 256 + tid) * 8, &Bs[0][(k * 256 + tid) * 8]);
    }
    __syncthreads();

    int buf = 0;
#pragma unroll 2
    for (int it = 0; it < KD / BK; ++it) {
        if (it + 1 < KD / BK) {
            const size_t off = (size_t)(it + 1) * 8192;   // u16 per BK=128 slab
#pragma unroll
            for (int k = 0; k < 4; ++k) {
                gl_lds16(abase + off + (k * 256 + tid) * 8, &As[buf ^ 1][(k * 256 + tid) * 8]);
                gl_lds16(bbase + off + (k * 256 + tid) * 8, &Bs[buf ^ 1][(k * 256 + tid) * 8]);
            }
        }
#pragma unroll
        for (int ks = 0; ks < 4; ++ks) {
            const int tb2 = (ks >> 1) * 512;   // which 64-col granule tile
            const int kl  = ks & 1;            // ks within tile
            bf16x8 av[2], bv[2];
#pragma unroll
            for (int mi = 0; mi < 2; ++mi)
                av[mi] = *(const bf16x8*)&As[buf][(tb2 + ((wr * 2 + kl) * 2 + mi) * 64 + lane) * 8];
#pragma unroll
            for (int ni = 0; ni < 2; ++ni)
                bv[ni] = *(const bf16x8*)&Bs[buf][(tb2 + ((wc * 2 + kl) * 2 + ni) * 64 + lane) * 8];
#pragma unroll
            for (int mi = 0; mi < 2; ++mi)
#pragma unroll
                for (int ni = 0; ni < 2; ++ni)
                    acc[mi][ni] = __builtin_amdgcn_mfma_f32_16x16x32_bf16(
                        av[mi], bv[ni], acc[mi][ni], 0, 0, 0);
        }
        __syncthreads();
        buf ^= 1;
    }

    // ---- epilogue: out[t, n*410+f] = A + sx[t][n]*G[f][n] + c[f] (proven R2) ----
#pragma unroll
    for (int ni = 0; ni < 2; ++ni) {
        const int fl = wc * 32 + ni * 16 + ml;
        const int fg = fb * BN + fl;
        if (fg >= NSF) continue;
        const float cv = cs[fl];
        float gv[NPARTS];
#pragma unroll
        for (int n = 0; n < NPARTS; ++n) gv[n] = Gs[fl][n];
#pragma unroll
        for (int mi = 0; mi < 2; ++mi) {
#pragma unroll
            for (int r = 0; r < 4; ++r) {
                const int tl = wr * 32 + mi * 16 + q * 4 + r;
                const float av = acc[mi][ni][r] + cv;
                float* orow = out + (size_t)(tb * BM + tl) * OUTF;
#pragma unroll
                for (int n = 0; n < NPARTS; ++n) {
                    int j = n * NSF + fg;
                    if (j < OUTF) orow[j] = av + sxs[tl][n] * gv[n];
                }
            }
        }
    }
}

extern "C" void kernel_launch(void* const* d_in, const int* in_sizes, int n_in,
                              void* d_out, int out_size, void* d_ws, size_t ws_size,
                              hipStream_t stream) {
    const float* x    = (const float*)d_in[0];
    const float* Wsel = (const float*)d_in[1];
    const float* bsel = (const float*)d_in[2];
    const float* Wexp = (const float*)d_in[3];
    const float* bexp = (const float*)d_in[4];
    const float* Wfc  = (const float*)d_in[5];
    const float* bfc  = (const float*)d_in[6];
    float* out = (float*)d_out;

    char* ws = (char*)d_ws;
    u16*   xb   = (u16*)  (ws + WS_XB);
    u16*   bsw  = (u16*)  (ws + WS_BSW);
    float* G    = (float*)(ws + WS_G);
    float* c    = (float*)(ws + WS_C);
    float* sx   = (float*)(ws + WS_SX);
    float* WT   = (float*)(ws + WS_WT);

    prep_a<<<dim3(16), dim3(256), 0, stream>>>(Wexp, bexp, WT);
    retile_b<<<dim3(7 * 64), dim3(256), 0, stream>>>(Wfc, bsw);
    prep_b<<<dim3(NSF), dim3(256), 0, stream>>>(Wfc, bfc, WT, G, c);
    sel_kernel<<<dim3(TKS / 8), dim3(256), 0, stream>>>(x, Wsel, bsel, sx);
    retile_x<<<dim3(64 * 64), dim3(256), 0, stream>>>(x, xb);
    main_kernel<<<dim3(7 * 64), dim3(256), 0, stream>>>(xb, bsw, G, c, sx, out);
}